// Round 2
// baseline (9638.622 us; speedup 1.0000x reference)
//
#include <hip/hip_runtime.h>
#include <cstdint>
#include <cstddef>

// ---------------------------------------------------------------------------
// GCNClassifier: 3x (GCNConv + tanh) + linear head, N=100k nodes, E=3.2M edges
// gcn_conv: agg[v] = sum_{(u->v) in E} h[u]*dinv[u]*dinv[v] + h[v]*dinv[v]^2 + b
// with deg[v] = |{e: dst(e)==v}| + 1 (self loop), dinv = 1/sqrt(deg)
// NOTE: edge_index arrives as int32 (harness converts all integer inputs).
// ---------------------------------------------------------------------------

__global__ void deg_count_kernel(const int* __restrict__ ei, int E,
                                 int* __restrict__ deg) {
    int i = blockIdx.x * blockDim.x + threadIdx.x;
    if (i < E) {
        int d = ei[(size_t)E + i];   // dst row of edge_index
        atomicAdd(&deg[d], 1);
    }
}

__global__ void dinv_kernel(const int* __restrict__ deg, float* __restrict__ dinv,
                            int n) {
    int v = blockIdx.x * blockDim.x + threadIdx.x;
    if (v < n) {
        float d = (float)(deg[v] + 1);    // +1 self loop; always > 0
        dinv[v] = 1.0f / sqrtf(d);
    }
}

// Dense GEMM h = X @ W, fused with self-loop init of the aggregation buffer:
//   H[v][f]   = (X@W)[v][f]
//   AGG[v][f] = H[v][f]*dinv[v]^2 + b[f]
// Block of 256 threads handles NPB node rows staged in LDS; each thread owns
// one output column f and RPT = NPB*FOUT/256 rows (4 FMA per W load).
template <int FIN, int FOUT, int NPB>
__global__ __launch_bounds__(256) void gemm_node(
    const float* __restrict__ X, const float* __restrict__ W,
    const float* __restrict__ B, const float* __restrict__ dinv,
    float* __restrict__ H, float* __restrict__ AGG, int n) {
    constexpr int RPT = (NPB * FOUT) / 256;   // rows per thread
    constexpr int RSTRIDE = 256 / FOUT;       // stride between a thread's rows
    constexpr int LROW = FIN + 4;             // +4 floats: break LDS bank aliasing
    __shared__ float xs[NPB][LROW];

    const int node0 = blockIdx.x * NPB;
    const int tid = threadIdx.x;

    // cooperative staging of NPB rows (float4)
    constexpr int C4 = FIN / 4;
    for (int i = tid; i < NPB * C4; i += 256) {
        int r = i / C4, c = i % C4;
        float4 v = make_float4(0.f, 0.f, 0.f, 0.f);
        if (node0 + r < n) v = *(const float4*)(X + (size_t)(node0 + r) * FIN + c * 4);
        *(float4*)&xs[r][c * 4] = v;
    }
    __syncthreads();

    const int f = tid % FOUT;
    const int r0 = tid / FOUT;
    float acc[RPT];
#pragma unroll
    for (int g = 0; g < RPT; ++g) acc[g] = 0.f;

    for (int k = 0; k < FIN; k += 4) {
        float w0 = W[(size_t)(k + 0) * FOUT + f];
        float w1 = W[(size_t)(k + 1) * FOUT + f];
        float w2 = W[(size_t)(k + 2) * FOUT + f];
        float w3 = W[(size_t)(k + 3) * FOUT + f];
#pragma unroll
        for (int g = 0; g < RPT; ++g) {
            int r = r0 + g * RSTRIDE;
            float4 xv = *(const float4*)&xs[r][k];
            acc[g] = fmaf(xv.x, w0, acc[g]);
            acc[g] = fmaf(xv.y, w1, acc[g]);
            acc[g] = fmaf(xv.z, w2, acc[g]);
            acc[g] = fmaf(xv.w, w3, acc[g]);
        }
    }

    float bf = B[f];
#pragma unroll
    for (int g = 0; g < RPT; ++g) {
        int node = node0 + r0 + g * RSTRIDE;
        if (node < n) {
            float di = dinv[node];
            size_t o = (size_t)node * FOUT + f;
            H[o] = acc[g];
            AGG[o] = fmaf(acc[g], di * di, bf);
        }
    }
}

// Edge scatter: F/4 threads per edge, float4 gather of H[src], scaled atomic
// scatter into AGG[dst].
template <int F>
__global__ __launch_bounds__(256) void edge_agg(
    const int* __restrict__ ei, int E, const float* __restrict__ H,
    const float* __restrict__ dinv, float* __restrict__ AGG) {
    constexpr int TPE = F / 4;  // threads per edge
    long long gid = (long long)blockIdx.x * blockDim.x + threadIdx.x;
    long long e = gid / TPE;
    int lane = (int)(gid % TPE);
    if (e >= E) return;
    int s = ei[e];
    int d = ei[(size_t)E + e];
    float nrm = dinv[s] * dinv[d];
    float4 v = *(const float4*)(H + (size_t)s * F + lane * 4);
    float* ap = AGG + (size_t)d * F + lane * 4;
    atomicAdd(ap + 0, v.x * nrm);
    atomicAdd(ap + 1, v.y * nrm);
    atomicAdd(ap + 2, v.z * nrm);
    atomicAdd(ap + 3, v.w * nrm);
}

__global__ void tanh_kernel(const float* __restrict__ src, float* __restrict__ dst,
                            long long count) {
    long long i = (long long)blockIdx.x * blockDim.x + threadIdx.x;
    if (i < count) dst[i] = tanhf(src[i]);
}

__global__ void classifier_kernel(const float* __restrict__ Hf,
                                  const float* __restrict__ Wc,
                                  const float* __restrict__ bc,
                                  float* __restrict__ out, int n) {
    int v = blockIdx.x * blockDim.x + threadIdx.x;
    if (v >= n) return;
    float o0 = bc[0], o1 = bc[1];
    const float* h = Hf + (size_t)v * 16;
#pragma unroll
    for (int k = 0; k < 16; ++k) {
        float hv = h[k];
        o0 = fmaf(hv, Wc[k * 2 + 0], o0);
        o1 = fmaf(hv, Wc[k * 2 + 1], o1);
    }
    out[(size_t)v * 2 + 0] = o0;
    out[(size_t)v * 2 + 1] = o1;
}

extern "C" void kernel_launch(void* const* d_in, const int* in_sizes, int n_in,
                              void* d_out, int out_size, void* d_ws, size_t ws_size,
                              hipStream_t stream) {
    const float* x   = (const float*)d_in[0];
    const int* ei    = (const int*)d_in[1];   // int32! harness converts int64 -> int32
    const float* W1  = (const float*)d_in[2];
    const float* b1  = (const float*)d_in[3];
    const float* W2  = (const float*)d_in[4];
    const float* b2  = (const float*)d_in[5];
    const float* W3  = (const float*)d_in[6];
    const float* b3  = (const float*)d_in[7];
    const float* Wc  = (const float*)d_in[8];
    const float* bc  = (const float*)d_in[9];

    const int n = in_sizes[0] / 256;
    const int E = in_sizes[1] / 2;

    float* outp = (float*)d_out;             // [n,2]
    float* outh = outp + (size_t)n * 2;      // [n,16]

    // workspace layout: deg(int n) | dinv(n) | bufA(n*128) | bufB(n*128)
    int* deg    = (int*)d_ws;
    float* dinv = (float*)d_ws + n;
    float* bufA = dinv + n;
    float* bufB = bufA + (size_t)n * 128;

    // --- degree / normalization (shared by all layers) ---
    hipMemsetAsync(deg, 0, sizeof(int) * (size_t)n, stream);
    deg_count_kernel<<<(E + 255) / 256, 256, 0, stream>>>(ei, E, deg);
    dinv_kernel<<<(n + 255) / 256, 256, 0, stream>>>(deg, dinv, n);

    // --- layer 1: 256 -> 128 ---
    gemm_node<256, 128, 8><<<(n + 7) / 8, 256, 0, stream>>>(x, W1, b1, dinv, bufA, bufB, n);
    {
        long long threads = (long long)E * (128 / 4);
        edge_agg<128><<<(int)((threads + 255) / 256), 256, 0, stream>>>(ei, E, bufA, dinv, bufB);
    }
    tanh_kernel<<<(int)(((long long)n * 128 + 255) / 256), 256, 0, stream>>>(
        bufB, bufB, (long long)n * 128);   // x2 = bufB

    // --- layer 2: 128 -> 64 ---
    {
        float* H2 = bufA;
        float* G2 = bufA + (size_t)n * 64;
        gemm_node<128, 64, 16><<<(n + 15) / 16, 256, 0, stream>>>(bufB, W2, b2, dinv, H2, G2, n);
        long long threads = (long long)E * (64 / 4);
        edge_agg<64><<<(int)((threads + 255) / 256), 256, 0, stream>>>(ei, E, H2, dinv, G2);
        tanh_kernel<<<(int)(((long long)n * 64 + 255) / 256), 256, 0, stream>>>(
            G2, G2, (long long)n * 64);    // x3 = bufA + n*64
    }

    // --- layer 3: 64 -> 16 ---
    {
        const float* X3 = bufA + (size_t)n * 64;
        float* H3 = bufB;
        float* G3 = bufB + (size_t)n * 16;
        gemm_node<64, 16, 64><<<(n + 63) / 64, 256, 0, stream>>>(X3, W3, b3, dinv, H3, G3, n);
        long long threads = (long long)E * (16 / 4);
        edge_agg<16><<<(int)((threads + 255) / 256), 256, 0, stream>>>(ei, E, H3, dinv, G3);
        tanh_kernel<<<(int)(((long long)n * 16 + 255) / 256), 256, 0, stream>>>(
            G3, outh, (long long)n * 16);  // h output
    }

    // --- classifier head: out = h @ Wc + bc ---
    classifier_kernel<<<(n + 255) / 256, 256, 0, stream>>>(outh, Wc, bc, outp, n);
}

// Round 3
// 1476.296 us; speedup vs baseline: 6.5289x; 6.5289x over previous
//
#include <hip/hip_runtime.h>
#include <cstdint>
#include <cstddef>

// ---------------------------------------------------------------------------
// GCNClassifier: 3x (GCNConv + tanh) + linear head, N=100k nodes, E=3.2M edges
// Round 3: CSR pull aggregation (no float atomics).
//   Hs[v]  = (X@W)[v] * dinv[v]                       (gemm epilogue)
//   out[v] = tanh( dinv[v]*(Hs[v] + sum_{u->v} Hs[u]) + b )   (pull, fused)
// CSR built per call: deg histogram -> 2-level scan -> cursor scatter.
// edge_index arrives as int32.
// ---------------------------------------------------------------------------

__global__ void deg_count_kernel(const int* __restrict__ ei, int E,
                                 int* __restrict__ deg) {
    int i = blockIdx.x * blockDim.x + threadIdx.x;
    if (i < E) atomicAdd(&deg[ei[(size_t)E + i]], 1);
}

__global__ void dinv_kernel(const int* __restrict__ deg, float* __restrict__ dinv,
                            int n) {
    int v = blockIdx.x * blockDim.x + threadIdx.x;
    if (v < n) dinv[v] = 1.0f / sqrtf((float)(deg[v] + 1));  // +1 self loop
}

// --- two-level exclusive scan over deg -> row_start ---
__global__ __launch_bounds__(256) void scan_block(const int* __restrict__ deg, int n,
                                                  int* __restrict__ incl,
                                                  int* __restrict__ bsum) {
    int tid = threadIdx.x;
    int v = blockIdx.x * 256 + tid;
    int val = (v < n) ? deg[v] : 0;
    int lane = tid & 63, w = tid >> 6;
#pragma unroll
    for (int off = 1; off < 64; off <<= 1) {
        int t = __shfl_up(val, off, 64);
        if (lane >= off) val += t;
    }
    __shared__ int wsum[4];
    if (lane == 63) wsum[w] = val;
    __syncthreads();
#pragma unroll
    for (int i = 0; i < 4; ++i)
        if (i < w) val += wsum[i];
    if (v < n) incl[v] = val;           // block-local inclusive scan
    if (tid == 255) bsum[blockIdx.x] = val;
}

__global__ __launch_bounds__(512) void scan_sums(int* __restrict__ bsum, int nb) {
    int tid = threadIdx.x;              // nb <= 512
    int val = (tid < nb) ? bsum[tid] : 0;
    int lane = tid & 63, w = tid >> 6;
#pragma unroll
    for (int off = 1; off < 64; off <<= 1) {
        int t = __shfl_up(val, off, 64);
        if (lane >= off) val += t;
    }
    __shared__ int wsum[8];
    if (lane == 63) wsum[w] = val;
    __syncthreads();
#pragma unroll
    for (int i = 0; i < 8; ++i)
        if (i < w) val += wsum[i];
    if (tid < nb) bsum[tid] = val;      // inclusive, in place
}

__global__ __launch_bounds__(256) void finalize_csr(
    const int* __restrict__ incl, const int* __restrict__ bsum,
    const int* __restrict__ deg, int n,
    int* __restrict__ row_start, int* __restrict__ cursor) {
    int tid = threadIdx.x;
    int v = blockIdx.x * 256 + tid;
    if (v >= n) return;
    int boff = (blockIdx.x == 0) ? 0 : bsum[blockIdx.x - 1];
    int rs = boff + incl[v] - deg[v];   // exclusive scan
    row_start[v] = rs;
    cursor[v] = rs;
}

__global__ void scatter_csr(const int* __restrict__ ei, int E,
                            int* __restrict__ cursor, int* __restrict__ col) {
    int i = blockIdx.x * blockDim.x + threadIdx.x;
    if (i < E) {
        int s = ei[i], d = ei[(size_t)E + i];
        int pos = atomicAdd(&cursor[d], 1);
        col[pos] = s;
    }
}

// Dense GEMM Hs = (X @ W) * dinv[v], LDS-staged node rows.
template <int FIN, int FOUT, int NPB>
__global__ __launch_bounds__(256) void gemm_node(
    const float* __restrict__ X, const float* __restrict__ W,
    const float* __restrict__ dinv, float* __restrict__ Hs, int n) {
    constexpr int RPT = (NPB * FOUT) / 256;
    constexpr int RSTRIDE = 256 / FOUT;
    constexpr int LROW = FIN + 4;
    __shared__ float xs[NPB][LROW];

    const int node0 = blockIdx.x * NPB;
    const int tid = threadIdx.x;
    constexpr int C4 = FIN / 4;
    for (int i = tid; i < NPB * C4; i += 256) {
        int r = i / C4, c = i % C4;
        float4 v = make_float4(0.f, 0.f, 0.f, 0.f);
        if (node0 + r < n) v = *(const float4*)(X + (size_t)(node0 + r) * FIN + c * 4);
        *(float4*)&xs[r][c * 4] = v;
    }
    __syncthreads();

    const int f = tid % FOUT;
    const int r0 = tid / FOUT;
    float acc[RPT];
#pragma unroll
    for (int g = 0; g < RPT; ++g) acc[g] = 0.f;

    for (int k = 0; k < FIN; k += 4) {
        float w0 = W[(size_t)(k + 0) * FOUT + f];
        float w1 = W[(size_t)(k + 1) * FOUT + f];
        float w2 = W[(size_t)(k + 2) * FOUT + f];
        float w3 = W[(size_t)(k + 3) * FOUT + f];
#pragma unroll
        for (int g = 0; g < RPT; ++g) {
            int r = r0 + g * RSTRIDE;
            float4 xv = *(const float4*)&xs[r][k];
            acc[g] = fmaf(xv.x, w0, acc[g]);
            acc[g] = fmaf(xv.y, w1, acc[g]);
            acc[g] = fmaf(xv.z, w2, acc[g]);
            acc[g] = fmaf(xv.w, w3, acc[g]);
        }
    }
#pragma unroll
    for (int g = 0; g < RPT; ++g) {
        int node = node0 + r0 + g * RSTRIDE;
        if (node < n) Hs[(size_t)node * FOUT + f] = acc[g] * dinv[node];
    }
}

// Pull aggregation + norm + bias + tanh, F/4 lanes per dst node.
template <int F>
__global__ __launch_bounds__(256) void pull_agg(
    const int* __restrict__ row_start, const int* __restrict__ deg,
    const int* __restrict__ col, const float* __restrict__ Hs,
    const float* __restrict__ dinv, const float* __restrict__ B,
    float* __restrict__ OUT, int n) {
    constexpr int TPE = F / 4;
    long long gid = (long long)blockIdx.x * 256 + threadIdx.x;
    int node = (int)(gid / TPE);
    int lane = (int)(gid % TPE);
    if (node >= n) return;
    const int beg = row_start[node];
    const int cnt = deg[node];
    const size_t lo = (size_t)lane * 4;

    float4 acc = *(const float4*)(Hs + (size_t)node * F + lo);  // self term
    int j = 0;
    for (; j + 4 <= cnt; j += 4) {
        int s0 = col[beg + j + 0], s1 = col[beg + j + 1];
        int s2 = col[beg + j + 2], s3 = col[beg + j + 3];
        float4 v0 = *(const float4*)(Hs + (size_t)s0 * F + lo);
        float4 v1 = *(const float4*)(Hs + (size_t)s1 * F + lo);
        float4 v2 = *(const float4*)(Hs + (size_t)s2 * F + lo);
        float4 v3 = *(const float4*)(Hs + (size_t)s3 * F + lo);
        acc.x += (v0.x + v1.x) + (v2.x + v3.x);
        acc.y += (v0.y + v1.y) + (v2.y + v3.y);
        acc.z += (v0.z + v1.z) + (v2.z + v3.z);
        acc.w += (v0.w + v1.w) + (v2.w + v3.w);
    }
    for (; j < cnt; ++j) {
        int s = col[beg + j];
        float4 v = *(const float4*)(Hs + (size_t)s * F + lo);
        acc.x += v.x; acc.y += v.y; acc.z += v.z; acc.w += v.w;
    }
    float di = dinv[node];
    float4 bb = *(const float4*)(B + lo);
    float4 r;
    r.x = tanhf(fmaf(acc.x, di, bb.x));
    r.y = tanhf(fmaf(acc.y, di, bb.y));
    r.z = tanhf(fmaf(acc.z, di, bb.z));
    r.w = tanhf(fmaf(acc.w, di, bb.w));
    *(float4*)(OUT + (size_t)node * F + lo) = r;
}

__global__ void classifier_kernel(const float* __restrict__ Hf,
                                  const float* __restrict__ Wc,
                                  const float* __restrict__ bc,
                                  float* __restrict__ out, int n) {
    int v = blockIdx.x * blockDim.x + threadIdx.x;
    if (v >= n) return;
    float o0 = bc[0], o1 = bc[1];
    const float* h = Hf + (size_t)v * 16;
#pragma unroll
    for (int k = 0; k < 16; ++k) {
        float hv = h[k];
        o0 = fmaf(hv, Wc[k * 2 + 0], o0);
        o1 = fmaf(hv, Wc[k * 2 + 1], o1);
    }
    out[(size_t)v * 2 + 0] = o0;
    out[(size_t)v * 2 + 1] = o1;
}

extern "C" void kernel_launch(void* const* d_in, const int* in_sizes, int n_in,
                              void* d_out, int out_size, void* d_ws, size_t ws_size,
                              hipStream_t stream) {
    const float* x  = (const float*)d_in[0];
    const int* ei   = (const int*)d_in[1];   // int32 (harness converts)
    const float* W1 = (const float*)d_in[2];
    const float* b1 = (const float*)d_in[3];
    const float* W2 = (const float*)d_in[4];
    const float* b2 = (const float*)d_in[5];
    const float* W3 = (const float*)d_in[6];
    const float* b3 = (const float*)d_in[7];
    const float* Wc = (const float*)d_in[8];
    const float* bc = (const float*)d_in[9];

    const int n = in_sizes[0] / 256;
    const int E = in_sizes[1] / 2;
    const int nb = (n + 255) / 256;          // scan blocks (391 <= 512)

    float* outp = (float*)d_out;             // [n,2]
    float* outh = outp + (size_t)n * 2;      // [n,16]

    // workspace: deg | dinv | row_start | cursor | incl | bsum(512) | col(E) | bufA | bufB
    int*   deg       = (int*)d_ws;
    float* dinv      = (float*)d_ws + (size_t)n;
    int*   row_start = (int*)d_ws + 2 * (size_t)n;
    int*   cursor    = (int*)d_ws + 3 * (size_t)n;
    int*   incl      = (int*)d_ws + 4 * (size_t)n;
    int*   bsum      = (int*)d_ws + 5 * (size_t)n;
    int*   col       = bsum + 512;
    float* bufA      = (float*)(col + E);
    float* bufB      = bufA + (size_t)n * 128;

    // --- CSR build (shared by all 3 layers) ---
    hipMemsetAsync(deg, 0, sizeof(int) * (size_t)n, stream);
    deg_count_kernel<<<(E + 255) / 256, 256, 0, stream>>>(ei, E, deg);
    dinv_kernel<<<nb, 256, 0, stream>>>(deg, dinv, n);
    scan_block<<<nb, 256, 0, stream>>>(deg, n, incl, bsum);
    scan_sums<<<1, 512, 0, stream>>>(bsum, nb);
    finalize_csr<<<nb, 256, 0, stream>>>(incl, bsum, deg, n, row_start, cursor);
    scatter_csr<<<(E + 255) / 256, 256, 0, stream>>>(ei, E, cursor, col);

    // --- layer 1: 256 -> 128 ---
    gemm_node<256, 128, 8><<<(n + 7) / 8, 256, 0, stream>>>(x, W1, dinv, bufA, n);
    pull_agg<128><<<(int)(((long long)n * 32 + 255) / 256), 256, 0, stream>>>(
        row_start, deg, col, bufA, dinv, b1, bufB, n);

    // --- layer 2: 128 -> 64 ---
    gemm_node<128, 64, 16><<<(n + 15) / 16, 256, 0, stream>>>(bufB, W2, dinv, bufA, n);
    pull_agg<64><<<(int)(((long long)n * 16 + 255) / 256), 256, 0, stream>>>(
        row_start, deg, col, bufA, dinv, b2, bufB, n);

    // --- layer 3: 64 -> 16 ---
    gemm_node<64, 16, 64><<<(n + 63) / 64, 256, 0, stream>>>(bufB, W3, dinv, bufA, n);
    pull_agg<16><<<(int)(((long long)n * 4 + 255) / 256), 256, 0, stream>>>(
        row_start, deg, col, bufA, dinv, b3, outh, n);

    // --- classifier head ---
    classifier_kernel<<<(n + 255) / 256, 256, 0, stream>>>(outh, Wc, bc, outp, n);
}

// Round 4
// 1124.802 us; speedup vs baseline: 8.5692x; 1.3125x over previous
//
#include <hip/hip_runtime.h>
#include <cstdint>
#include <cstddef>

// ---------------------------------------------------------------------------
// GCNClassifier: 3x (GCNConv + tanh) + linear head, N=100k nodes, E=3.2M edges
// Round 4: register-tiled GEMM (4x4 acc per thread) replaces the spilling
// gemm_node (VGPR=256, 806 MB scratch writes -> memory-bound at 367 us).
//   Hs[v]  = (X@W)[v] * dinv[v]                       (gemm epilogue)
//   out[v] = tanh( dinv[v]*(Hs[v] + sum_{u->v} Hs[u]) + b )   (pull, fused)
// edge_index arrives as int32.
// ---------------------------------------------------------------------------

__global__ void deg_count_kernel(const int* __restrict__ ei, int E,
                                 int* __restrict__ deg) {
    int i = blockIdx.x * blockDim.x + threadIdx.x;
    if (i < E) atomicAdd(&deg[ei[(size_t)E + i]], 1);
}

__global__ void dinv_kernel(const int* __restrict__ deg, float* __restrict__ dinv,
                            int n) {
    int v = blockIdx.x * blockDim.x + threadIdx.x;
    if (v < n) dinv[v] = 1.0f / sqrtf((float)(deg[v] + 1));  // +1 self loop
}

// --- two-level exclusive scan over deg -> row_start ---
__global__ __launch_bounds__(256) void scan_block(const int* __restrict__ deg, int n,
                                                  int* __restrict__ incl,
                                                  int* __restrict__ bsum) {
    int tid = threadIdx.x;
    int v = blockIdx.x * 256 + tid;
    int val = (v < n) ? deg[v] : 0;
    int lane = tid & 63, w = tid >> 6;
#pragma unroll
    for (int off = 1; off < 64; off <<= 1) {
        int t = __shfl_up(val, off, 64);
        if (lane >= off) val += t;
    }
    __shared__ int wsum[4];
    if (lane == 63) wsum[w] = val;
    __syncthreads();
#pragma unroll
    for (int i = 0; i < 4; ++i)
        if (i < w) val += wsum[i];
    if (v < n) incl[v] = val;           // block-local inclusive scan
    if (tid == 255) bsum[blockIdx.x] = val;
}

__global__ __launch_bounds__(512) void scan_sums(int* __restrict__ bsum, int nb) {
    int tid = threadIdx.x;              // nb <= 512
    int val = (tid < nb) ? bsum[tid] : 0;
    int lane = tid & 63, w = tid >> 6;
#pragma unroll
    for (int off = 1; off < 64; off <<= 1) {
        int t = __shfl_up(val, off, 64);
        if (lane >= off) val += t;
    }
    __shared__ int wsum[8];
    if (lane == 63) wsum[w] = val;
    __syncthreads();
#pragma unroll
    for (int i = 0; i < 8; ++i)
        if (i < w) val += wsum[i];
    if (tid < nb) bsum[tid] = val;      // inclusive, in place
}

__global__ __launch_bounds__(256) void finalize_csr(
    const int* __restrict__ incl, const int* __restrict__ bsum,
    const int* __restrict__ deg, int n,
    int* __restrict__ row_start, int* __restrict__ cursor) {
    int tid = threadIdx.x;
    int v = blockIdx.x * 256 + tid;
    if (v >= n) return;
    int boff = (blockIdx.x == 0) ? 0 : bsum[blockIdx.x - 1];
    int rs = boff + incl[v] - deg[v];   // exclusive scan
    row_start[v] = rs;
    cursor[v] = rs;
}

__global__ void scatter_csr(const int* __restrict__ ei, int E,
                            int* __restrict__ cursor, int* __restrict__ col) {
    int i = blockIdx.x * blockDim.x + threadIdx.x;
    if (i < E) {
        int s = ei[i], d = ei[(size_t)E + i];
        int pos = atomicAdd(&cursor[d], 1);
        col[pos] = s;
    }
}

// Register-tiled GEMM: Hs = (X @ W) * dinv[row].
// 256 threads: CT=FOUT/4 col-groups x RG=256/CT row-groups; each thread owns
// 4 rows x 4 cols (16 accumulators). X tile staged in LDS (whole FIN rows,
// LROW=FIN+4 so float4 staging stays aligned & conflict-free; a-reads are
// broadcast across the CT lanes of a wave). W read as float4 straight from
// global: all RG row-groups hit the same line -> L1-resident.
template <int FIN, int FOUT, int TM>
__global__ __launch_bounds__(256) void gemm_tile(
    const float* __restrict__ X, const float* __restrict__ W,
    const float* __restrict__ dinv, float* __restrict__ Hs, int n) {
    constexpr int CT = FOUT / 4;          // col-groups
    constexpr int RG = 256 / CT;          // row-groups
    static_assert(TM == RG * 4, "tile mismatch");
    constexpr int LROW = FIN + 4;         // float4-aligned, staggers banks
    __shared__ float xs[TM][LROW];

    const int node0 = blockIdx.x * TM;
    const int tid = threadIdx.x;

    // stage TM rows, float4-coalesced, float4 LDS writes (conflict-free)
    constexpr int C4 = FIN / 4;
    for (int i = tid; i < TM * C4; i += 256) {
        int r = i / C4, c = i % C4;
        float4 v = make_float4(0.f, 0.f, 0.f, 0.f);
        if (node0 + r < n) v = *(const float4*)(X + (size_t)(node0 + r) * FIN + c * 4);
        *(float4*)&xs[r][c * 4] = v;
    }
    __syncthreads();

    const int col = (tid % CT) * 4;
    const int r0 = (tid / CT) * 4;

    float acc[4][4];
#pragma unroll
    for (int i = 0; i < 4; ++i)
#pragma unroll
        for (int j = 0; j < 4; ++j) acc[i][j] = 0.f;

#pragma unroll 8
    for (int k = 0; k < FIN; ++k) {
        float4 b = *(const float4*)(W + (size_t)k * FOUT + col);
        float a0 = xs[r0 + 0][k];
        float a1 = xs[r0 + 1][k];
        float a2 = xs[r0 + 2][k];
        float a3 = xs[r0 + 3][k];
        acc[0][0] = fmaf(a0, b.x, acc[0][0]); acc[0][1] = fmaf(a0, b.y, acc[0][1]);
        acc[0][2] = fmaf(a0, b.z, acc[0][2]); acc[0][3] = fmaf(a0, b.w, acc[0][3]);
        acc[1][0] = fmaf(a1, b.x, acc[1][0]); acc[1][1] = fmaf(a1, b.y, acc[1][1]);
        acc[1][2] = fmaf(a1, b.z, acc[1][2]); acc[1][3] = fmaf(a1, b.w, acc[1][3]);
        acc[2][0] = fmaf(a2, b.x, acc[2][0]); acc[2][1] = fmaf(a2, b.y, acc[2][1]);
        acc[2][2] = fmaf(a2, b.z, acc[2][2]); acc[2][3] = fmaf(a2, b.w, acc[2][3]);
        acc[3][0] = fmaf(a3, b.x, acc[3][0]); acc[3][1] = fmaf(a3, b.y, acc[3][1]);
        acc[3][2] = fmaf(a3, b.z, acc[3][2]); acc[3][3] = fmaf(a3, b.w, acc[3][3]);
    }

#pragma unroll
    for (int rr = 0; rr < 4; ++rr) {
        int node = node0 + r0 + rr;
        if (node < n) {
            float di = dinv[node];
            float4 o;
            o.x = acc[rr][0] * di; o.y = acc[rr][1] * di;
            o.z = acc[rr][2] * di; o.w = acc[rr][3] * di;
            *(float4*)(Hs + (size_t)node * FOUT + col) = o;
        }
    }
}

// Pull aggregation + norm + bias + tanh, F/4 lanes per dst node.
template <int F>
__global__ __launch_bounds__(256) void pull_agg(
    const int* __restrict__ row_start, const int* __restrict__ deg,
    const int* __restrict__ col, const float* __restrict__ Hs,
    const float* __restrict__ dinv, const float* __restrict__ B,
    float* __restrict__ OUT, int n) {
    constexpr int TPE = F / 4;
    long long gid = (long long)blockIdx.x * 256 + threadIdx.x;
    int node = (int)(gid / TPE);
    int lane = (int)(gid % TPE);
    if (node >= n) return;
    const int beg = row_start[node];
    const int cnt = deg[node];
    const size_t lo = (size_t)lane * 4;

    float4 acc = *(const float4*)(Hs + (size_t)node * F + lo);  // self term
    int j = 0;
    for (; j + 4 <= cnt; j += 4) {
        int s0 = col[beg + j + 0], s1 = col[beg + j + 1];
        int s2 = col[beg + j + 2], s3 = col[beg + j + 3];
        float4 v0 = *(const float4*)(Hs + (size_t)s0 * F + lo);
        float4 v1 = *(const float4*)(Hs + (size_t)s1 * F + lo);
        float4 v2 = *(const float4*)(Hs + (size_t)s2 * F + lo);
        float4 v3 = *(const float4*)(Hs + (size_t)s3 * F + lo);
        acc.x += (v0.x + v1.x) + (v2.x + v3.x);
        acc.y += (v0.y + v1.y) + (v2.y + v3.y);
        acc.z += (v0.z + v1.z) + (v2.z + v3.z);
        acc.w += (v0.w + v1.w) + (v2.w + v3.w);
    }
    for (; j < cnt; ++j) {
        int s = col[beg + j];
        float4 v = *(const float4*)(Hs + (size_t)s * F + lo);
        acc.x += v.x; acc.y += v.y; acc.z += v.z; acc.w += v.w;
    }
    float di = dinv[node];
    float4 bb = *(const float4*)(B + lo);
    float4 r;
    r.x = tanhf(fmaf(acc.x, di, bb.x));
    r.y = tanhf(fmaf(acc.y, di, bb.y));
    r.z = tanhf(fmaf(acc.z, di, bb.z));
    r.w = tanhf(fmaf(acc.w, di, bb.w));
    *(float4*)(OUT + (size_t)node * F + lo) = r;
}

__global__ void classifier_kernel(const float* __restrict__ Hf,
                                  const float* __restrict__ Wc,
                                  const float* __restrict__ bc,
                                  float* __restrict__ out, int n) {
    int v = blockIdx.x * blockDim.x + threadIdx.x;
    if (v >= n) return;
    float o0 = bc[0], o1 = bc[1];
    const float* h = Hf + (size_t)v * 16;
#pragma unroll
    for (int k = 0; k < 16; ++k) {
        float hv = h[k];
        o0 = fmaf(hv, Wc[k * 2 + 0], o0);
        o1 = fmaf(hv, Wc[k * 2 + 1], o1);
    }
    out[(size_t)v * 2 + 0] = o0;
    out[(size_t)v * 2 + 1] = o1;
}

extern "C" void kernel_launch(void* const* d_in, const int* in_sizes, int n_in,
                              void* d_out, int out_size, void* d_ws, size_t ws_size,
                              hipStream_t stream) {
    const float* x  = (const float*)d_in[0];
    const int* ei   = (const int*)d_in[1];   // int32 (harness converts)
    const float* W1 = (const float*)d_in[2];
    const float* b1 = (const float*)d_in[3];
    const float* W2 = (const float*)d_in[4];
    const float* b2 = (const float*)d_in[5];
    const float* W3 = (const float*)d_in[6];
    const float* b3 = (const float*)d_in[7];
    const float* Wc = (const float*)d_in[8];
    const float* bc = (const float*)d_in[9];

    const int n = in_sizes[0] / 256;
    const int E = in_sizes[1] / 2;
    const int nb = (n + 255) / 256;          // scan blocks (391 <= 512)

    float* outp = (float*)d_out;             // [n,2]
    float* outh = outp + (size_t)n * 2;      // [n,16]

    // workspace: deg | dinv | row_start | cursor | incl | bsum(512) | col(E) | bufA | bufB
    int*   deg       = (int*)d_ws;
    float* dinv      = (float*)d_ws + (size_t)n;
    int*   row_start = (int*)d_ws + 2 * (size_t)n;
    int*   cursor    = (int*)d_ws + 3 * (size_t)n;
    int*   incl      = (int*)d_ws + 4 * (size_t)n;
    int*   bsum      = (int*)d_ws + 5 * (size_t)n;
    int*   col       = bsum + 512;
    float* bufA      = (float*)(col + E);
    float* bufB      = bufA + (size_t)n * 128;

    // --- CSR build (shared by all 3 layers) ---
    hipMemsetAsync(deg, 0, sizeof(int) * (size_t)n, stream);
    deg_count_kernel<<<(E + 255) / 256, 256, 0, stream>>>(ei, E, deg);
    dinv_kernel<<<nb, 256, 0, stream>>>(deg, dinv, n);
    scan_block<<<nb, 256, 0, stream>>>(deg, n, incl, bsum);
    scan_sums<<<1, 512, 0, stream>>>(bsum, nb);
    finalize_csr<<<nb, 256, 0, stream>>>(incl, bsum, deg, n, row_start, cursor);
    scatter_csr<<<(E + 255) / 256, 256, 0, stream>>>(ei, E, cursor, col);

    // --- layer 1: 256 -> 128 ---
    gemm_tile<256, 128, 32><<<(n + 31) / 32, 256, 0, stream>>>(x, W1, dinv, bufA, n);
    pull_agg<128><<<(int)(((long long)n * 32 + 255) / 256), 256, 0, stream>>>(
        row_start, deg, col, bufA, dinv, b1, bufB, n);

    // --- layer 2: 128 -> 64 ---
    gemm_tile<128, 64, 64><<<(n + 63) / 64, 256, 0, stream>>>(bufB, W2, dinv, bufA, n);
    pull_agg<64><<<(int)(((long long)n * 16 + 255) / 256), 256, 0, stream>>>(
        row_start, deg, col, bufA, dinv, b2, bufB, n);

    // --- layer 3: 64 -> 16 ---
    gemm_tile<64, 16, 256><<<(n + 255) / 256, 256, 0, stream>>>(bufB, W3, dinv, bufA, n);
    pull_agg<16><<<(int)(((long long)n * 4 + 255) / 256), 256, 0, stream>>>(
        row_start, deg, col, bufA, dinv, b3, outh, n);

    // --- classifier head ---
    classifier_kernel<<<(n + 255) / 256, 256, 0, stream>>>(outh, Wc, bc, outp, n);
}

// Round 5
// 986.486 us; speedup vs baseline: 9.7707x; 1.1402x over previous
//
#include <hip/hip_runtime.h>
#include <cstdint>
#include <cstddef>

// ---------------------------------------------------------------------------
// GCNClassifier: 3x (GCNConv + tanh) + linear head, N=100k nodes, E=3.2M edges
// Round 5: dst-partitioned CSR scatter. Round-4 scatter_csr wrote 199 MB HBM
// for a 12.8 MB col array (every 4-B scattered store evicted a partial line;
// window spread across 8 non-coherent L2s). Partitioning dst into 8 ranges
// (1.6 MB col window each) with partition = blockIdx.x & 7 (round-robin XCD
// mapping) keeps each window in one L2 -> full-line writebacks.
//   Hs[v]  = (X@W)[v] * dinv[v]                       (gemm epilogue)
//   out[v] = tanh( dinv[v]*(Hs[v] + sum_{u->v} Hs[u]) + b )   (pull, fused)
// edge_index arrives as int32.
// ---------------------------------------------------------------------------

__global__ void deg_count_kernel(const int* __restrict__ ei, int E,
                                 int* __restrict__ deg) {
    int i = blockIdx.x * blockDim.x + threadIdx.x;
    if (i < E) atomicAdd(&deg[ei[(size_t)E + i]], 1);
}

__global__ void dinv_kernel(const int* __restrict__ deg, float* __restrict__ dinv,
                            int n) {
    int v = blockIdx.x * blockDim.x + threadIdx.x;
    if (v < n) dinv[v] = 1.0f / sqrtf((float)(deg[v] + 1));  // +1 self loop
}

// --- two-level exclusive scan over deg -> row_start ---
__global__ __launch_bounds__(256) void scan_block(const int* __restrict__ deg, int n,
                                                  int* __restrict__ incl,
                                                  int* __restrict__ bsum) {
    int tid = threadIdx.x;
    int v = blockIdx.x * 256 + tid;
    int val = (v < n) ? deg[v] : 0;
    int lane = tid & 63, w = tid >> 6;
#pragma unroll
    for (int off = 1; off < 64; off <<= 1) {
        int t = __shfl_up(val, off, 64);
        if (lane >= off) val += t;
    }
    __shared__ int wsum[4];
    if (lane == 63) wsum[w] = val;
    __syncthreads();
#pragma unroll
    for (int i = 0; i < 4; ++i)
        if (i < w) val += wsum[i];
    if (v < n) incl[v] = val;           // block-local inclusive scan
    if (tid == 255) bsum[blockIdx.x] = val;
}

__global__ __launch_bounds__(512) void scan_sums(int* __restrict__ bsum, int nb) {
    int tid = threadIdx.x;              // nb <= 512
    int val = (tid < nb) ? bsum[tid] : 0;
    int lane = tid & 63, w = tid >> 6;
#pragma unroll
    for (int off = 1; off < 64; off <<= 1) {
        int t = __shfl_up(val, off, 64);
        if (lane >= off) val += t;
    }
    __shared__ int wsum[8];
    if (lane == 63) wsum[w] = val;
    __syncthreads();
#pragma unroll
    for (int i = 0; i < 8; ++i)
        if (i < w) val += wsum[i];
    if (tid < nb) bsum[tid] = val;      // inclusive, in place
}

__global__ __launch_bounds__(256) void finalize_csr(
    const int* __restrict__ incl, const int* __restrict__ bsum,
    const int* __restrict__ deg, int n,
    int* __restrict__ row_start, int* __restrict__ cursor) {
    int tid = threadIdx.x;
    int v = blockIdx.x * 256 + tid;
    if (v >= n) return;
    int boff = (blockIdx.x == 0) ? 0 : bsum[blockIdx.x - 1];
    int rs = boff + incl[v] - deg[v];   // exclusive scan
    row_start[v] = rs;
    cursor[v] = rs;
}

// dst-partitioned scatter: block (part = b&7, chunk = b>>3) scans edge chunk,
// processes only edges whose dst falls in partition `part` (contiguous dst
// range of ~n/8 nodes -> ~1.6 MB col window, L2-resident under %8 XCD
// round-robin). Edges are read 8x (LLC-absorbed); 7/8 lanes predicate off.
#define SCAT_EPB 8192
__global__ __launch_bounds__(256) void scatter_csr_part(
    const int* __restrict__ ei, int E, float inv_psz,
    int* __restrict__ cursor, int* __restrict__ col) {
    const int part = blockIdx.x & 7;
    const int base = (blockIdx.x >> 3) * SCAT_EPB;
    const int end = min(E, base + SCAT_EPB);
    for (int i = base + threadIdx.x; i < end; i += 256) {
        int d = ei[(size_t)E + i];
        int s = ei[i];                       // unconditional: keeps load coalesced
        int p = (int)((float)d * inv_psz);   // deterministic partition id
        p = p > 7 ? 7 : p;
        if (p == part) {
            int pos = atomicAdd(&cursor[d], 1);
            col[pos] = s;
        }
    }
}

// Register-tiled GEMM: Hs = (X @ W) * dinv[row]. 4x4 acc per thread, X tile
// in LDS (LROW=FIN+4 keeps float4 staging aligned), W float4 from global
// (L1-resident: all row-groups share the same line).
template <int FIN, int FOUT, int TM>
__global__ __launch_bounds__(256) void gemm_tile(
    const float* __restrict__ X, const float* __restrict__ W,
    const float* __restrict__ dinv, float* __restrict__ Hs, int n) {
    constexpr int CT = FOUT / 4;          // col-groups
    constexpr int RG = 256 / CT;          // row-groups
    static_assert(TM == RG * 4, "tile mismatch");
    constexpr int LROW = FIN + 4;
    __shared__ float xs[TM][LROW];

    const int node0 = blockIdx.x * TM;
    const int tid = threadIdx.x;

    constexpr int C4 = FIN / 4;
    for (int i = tid; i < TM * C4; i += 256) {
        int r = i / C4, c = i % C4;
        float4 v = make_float4(0.f, 0.f, 0.f, 0.f);
        if (node0 + r < n) v = *(const float4*)(X + (size_t)(node0 + r) * FIN + c * 4);
        *(float4*)&xs[r][c * 4] = v;
    }
    __syncthreads();

    const int col = (tid % CT) * 4;
    const int r0 = (tid / CT) * 4;

    float acc[4][4];
#pragma unroll
    for (int i = 0; i < 4; ++i)
#pragma unroll
        for (int j = 0; j < 4; ++j) acc[i][j] = 0.f;

#pragma unroll 8
    for (int k = 0; k < FIN; ++k) {
        float4 b = *(const float4*)(W + (size_t)k * FOUT + col);
        float a0 = xs[r0 + 0][k];
        float a1 = xs[r0 + 1][k];
        float a2 = xs[r0 + 2][k];
        float a3 = xs[r0 + 3][k];
        acc[0][0] = fmaf(a0, b.x, acc[0][0]); acc[0][1] = fmaf(a0, b.y, acc[0][1]);
        acc[0][2] = fmaf(a0, b.z, acc[0][2]); acc[0][3] = fmaf(a0, b.w, acc[0][3]);
        acc[1][0] = fmaf(a1, b.x, acc[1][0]); acc[1][1] = fmaf(a1, b.y, acc[1][1]);
        acc[1][2] = fmaf(a1, b.z, acc[1][2]); acc[1][3] = fmaf(a1, b.w, acc[1][3]);
        acc[2][0] = fmaf(a2, b.x, acc[2][0]); acc[2][1] = fmaf(a2, b.y, acc[2][1]);
        acc[2][2] = fmaf(a2, b.z, acc[2][2]); acc[2][3] = fmaf(a2, b.w, acc[2][3]);
        acc[3][0] = fmaf(a3, b.x, acc[3][0]); acc[3][1] = fmaf(a3, b.y, acc[3][1]);
        acc[3][2] = fmaf(a3, b.z, acc[3][2]); acc[3][3] = fmaf(a3, b.w, acc[3][3]);
    }

#pragma unroll
    for (int rr = 0; rr < 4; ++rr) {
        int node = node0 + r0 + rr;
        if (node < n) {
            float di = dinv[node];
            float4 o;
            o.x = acc[rr][0] * di; o.y = acc[rr][1] * di;
            o.z = acc[rr][2] * di; o.w = acc[rr][3] * di;
            *(float4*)(Hs + (size_t)node * FOUT + col) = o;
        }
    }
}

// Pull aggregation + norm + bias + tanh, F/4 lanes per dst node.
template <int F>
__global__ __launch_bounds__(256) void pull_agg(
    const int* __restrict__ row_start, const int* __restrict__ deg,
    const int* __restrict__ col, const float* __restrict__ Hs,
    const float* __restrict__ dinv, const float* __restrict__ B,
    float* __restrict__ OUT, int n) {
    constexpr int TPE = F / 4;
    long long gid = (long long)blockIdx.x * 256 + threadIdx.x;
    int node = (int)(gid / TPE);
    int lane = (int)(gid % TPE);
    if (node >= n) return;
    const int beg = row_start[node];
    const int cnt = deg[node];
    const size_t lo = (size_t)lane * 4;

    float4 acc = *(const float4*)(Hs + (size_t)node * F + lo);  // self term
    int j = 0;
    for (; j + 4 <= cnt; j += 4) {
        int s0 = col[beg + j + 0], s1 = col[beg + j + 1];
        int s2 = col[beg + j + 2], s3 = col[beg + j + 3];
        float4 v0 = *(const float4*)(Hs + (size_t)s0 * F + lo);
        float4 v1 = *(const float4*)(Hs + (size_t)s1 * F + lo);
        float4 v2 = *(const float4*)(Hs + (size_t)s2 * F + lo);
        float4 v3 = *(const float4*)(Hs + (size_t)s3 * F + lo);
        acc.x += (v0.x + v1.x) + (v2.x + v3.x);
        acc.y += (v0.y + v1.y) + (v2.y + v3.y);
        acc.z += (v0.z + v1.z) + (v2.z + v3.z);
        acc.w += (v0.w + v1.w) + (v2.w + v3.w);
    }
    for (; j < cnt; ++j) {
        int s = col[beg + j];
        float4 v = *(const float4*)(Hs + (size_t)s * F + lo);
        acc.x += v.x; acc.y += v.y; acc.z += v.z; acc.w += v.w;
    }
    float di = dinv[node];
    float4 bb = *(const float4*)(B + lo);
    float4 r;
    r.x = tanhf(fmaf(acc.x, di, bb.x));
    r.y = tanhf(fmaf(acc.y, di, bb.y));
    r.z = tanhf(fmaf(acc.z, di, bb.z));
    r.w = tanhf(fmaf(acc.w, di, bb.w));
    *(float4*)(OUT + (size_t)node * F + lo) = r;
}

__global__ void classifier_kernel(const float* __restrict__ Hf,
                                  const float* __restrict__ Wc,
                                  const float* __restrict__ bc,
                                  float* __restrict__ out, int n) {
    int v = blockIdx.x * blockDim.x + threadIdx.x;
    if (v >= n) return;
    float o0 = bc[0], o1 = bc[1];
    const float* h = Hf + (size_t)v * 16;
#pragma unroll
    for (int k = 0; k < 16; ++k) {
        float hv = h[k];
        o0 = fmaf(hv, Wc[k * 2 + 0], o0);
        o1 = fmaf(hv, Wc[k * 2 + 1], o1);
    }
    out[(size_t)v * 2 + 0] = o0;
    out[(size_t)v * 2 + 1] = o1;
}

extern "C" void kernel_launch(void* const* d_in, const int* in_sizes, int n_in,
                              void* d_out, int out_size, void* d_ws, size_t ws_size,
                              hipStream_t stream) {
    const float* x  = (const float*)d_in[0];
    const int* ei   = (const int*)d_in[1];   // int32 (harness converts)
    const float* W1 = (const float*)d_in[2];
    const float* b1 = (const float*)d_in[3];
    const float* W2 = (const float*)d_in[4];
    const float* b2 = (const float*)d_in[5];
    const float* W3 = (const float*)d_in[6];
    const float* b3 = (const float*)d_in[7];
    const float* Wc = (const float*)d_in[8];
    const float* bc = (const float*)d_in[9];

    const int n = in_sizes[0] / 256;
    const int E = in_sizes[1] / 2;
    const int nb = (n + 255) / 256;          // scan blocks (391 <= 512)

    float* outp = (float*)d_out;             // [n,2]
    float* outh = outp + (size_t)n * 2;      // [n,16]

    // workspace: deg | dinv | row_start | cursor | incl | bsum(512) | col(E) | bufA | bufB
    int*   deg       = (int*)d_ws;
    float* dinv      = (float*)d_ws + (size_t)n;
    int*   row_start = (int*)d_ws + 2 * (size_t)n;
    int*   cursor    = (int*)d_ws + 3 * (size_t)n;
    int*   incl      = (int*)d_ws + 4 * (size_t)n;
    int*   bsum      = (int*)d_ws + 5 * (size_t)n;
    int*   col       = bsum + 512;
    float* bufA      = (float*)(col + E);
    float* bufB      = bufA + (size_t)n * 128;

    // --- CSR build (shared by all 3 layers) ---
    hipMemsetAsync(deg, 0, sizeof(int) * (size_t)n, stream);
    deg_count_kernel<<<(E + 255) / 256, 256, 0, stream>>>(ei, E, deg);
    dinv_kernel<<<nb, 256, 0, stream>>>(deg, dinv, n);
    scan_block<<<nb, 256, 0, stream>>>(deg, n, incl, bsum);
    scan_sums<<<1, 512, 0, stream>>>(bsum, nb);
    finalize_csr<<<nb, 256, 0, stream>>>(incl, bsum, deg, n, row_start, cursor);
    {
        int psz = (n + 7) / 8;               // dst-partition size
        float inv_psz = 1.0f / (float)psz;
        int chunks = (E + SCAT_EPB - 1) / SCAT_EPB;
        scatter_csr_part<<<chunks * 8, 256, 0, stream>>>(ei, E, inv_psz, cursor, col);
    }

    // --- layer 1: 256 -> 128 ---
    gemm_tile<256, 128, 32><<<(n + 31) / 32, 256, 0, stream>>>(x, W1, dinv, bufA, n);
    pull_agg<128><<<(int)(((long long)n * 32 + 255) / 256), 256, 0, stream>>>(
        row_start, deg, col, bufA, dinv, b1, bufB, n);

    // --- layer 2: 128 -> 64 ---
    gemm_tile<128, 64, 64><<<(n + 63) / 64, 256, 0, stream>>>(bufB, W2, dinv, bufA, n);
    pull_agg<64><<<(int)(((long long)n * 16 + 255) / 256), 256, 0, stream>>>(
        row_start, deg, col, bufA, dinv, b2, bufB, n);

    // --- layer 3: 64 -> 16 ---
    gemm_tile<64, 16, 256><<<(n + 255) / 256, 256, 0, stream>>>(bufB, W3, dinv, bufA, n);
    pull_agg<16><<<(int)(((long long)n * 4 + 255) / 256), 256, 0, stream>>>(
        row_start, deg, col, bufA, dinv, b3, outh, n);

    // --- classifier head ---
    classifier_kernel<<<(n + 255) / 256, 256, 0, stream>>>(outh, Wc, bc, outp, n);
}

// Round 6
// 816.207 us; speedup vs baseline: 11.8090x; 1.2086x over previous
//
#include <hip/hip_runtime.h>
#include <hip/hip_fp16.h>
#include <cstdint>
#include <cstddef>

// ---------------------------------------------------------------------------
// GCNClassifier: 3x (GCNConv + tanh) + linear head, N=100k nodes, E=3.2M edges
// Round 6: fp16 gather buffers. Round-5 pull_agg<128> fetched 799 MB HBM for
// a 1.64 GB logical random-row gather (51 MB f32 Hs >> 32 MB aggregate L2).
// Storing Hs in fp16 halves row bytes (512->256 B) and doubles effective
// cache capacity. Accumulation stays f32; fp16 eps 2^-11 keeps absmax ~5e-4
// (threshold 1.845e-3). bf16 (2^-9) would have been marginal.
//   Hs[v]  = fp16( (X@W)[v] * dinv[v] )               (gemm epilogue)
//   out[v] = tanh( dinv[v]*(Hs[v] + sum_{u->v} Hs[u]) + b )   (pull, fused)
// edge_index arrives as int32.
// ---------------------------------------------------------------------------

__global__ void deg_count_kernel(const int* __restrict__ ei, int E,
                                 int* __restrict__ deg) {
    int i = blockIdx.x * blockDim.x + threadIdx.x;
    if (i < E) atomicAdd(&deg[ei[(size_t)E + i]], 1);
}

__global__ void dinv_kernel(const int* __restrict__ deg, float* __restrict__ dinv,
                            int n) {
    int v = blockIdx.x * blockDim.x + threadIdx.x;
    if (v < n) dinv[v] = 1.0f / sqrtf((float)(deg[v] + 1));  // +1 self loop
}

// --- two-level exclusive scan over deg -> row_start ---
__global__ __launch_bounds__(256) void scan_block(const int* __restrict__ deg, int n,
                                                  int* __restrict__ incl,
                                                  int* __restrict__ bsum) {
    int tid = threadIdx.x;
    int v = blockIdx.x * 256 + tid;
    int val = (v < n) ? deg[v] : 0;
    int lane = tid & 63, w = tid >> 6;
#pragma unroll
    for (int off = 1; off < 64; off <<= 1) {
        int t = __shfl_up(val, off, 64);
        if (lane >= off) val += t;
    }
    __shared__ int wsum[4];
    if (lane == 63) wsum[w] = val;
    __syncthreads();
#pragma unroll
    for (int i = 0; i < 4; ++i)
        if (i < w) val += wsum[i];
    if (v < n) incl[v] = val;           // block-local inclusive scan
    if (tid == 255) bsum[blockIdx.x] = val;
}

__global__ __launch_bounds__(512) void scan_sums(int* __restrict__ bsum, int nb) {
    int tid = threadIdx.x;              // nb <= 512
    int val = (tid < nb) ? bsum[tid] : 0;
    int lane = tid & 63, w = tid >> 6;
#pragma unroll
    for (int off = 1; off < 64; off <<= 1) {
        int t = __shfl_up(val, off, 64);
        if (lane >= off) val += t;
    }
    __shared__ int wsum[8];
    if (lane == 63) wsum[w] = val;
    __syncthreads();
#pragma unroll
    for (int i = 0; i < 8; ++i)
        if (i < w) val += wsum[i];
    if (tid < nb) bsum[tid] = val;      // inclusive, in place
}

__global__ __launch_bounds__(256) void finalize_csr(
    const int* __restrict__ incl, const int* __restrict__ bsum,
    const int* __restrict__ deg, int n,
    int* __restrict__ row_start, int* __restrict__ cursor) {
    int tid = threadIdx.x;
    int v = blockIdx.x * 256 + tid;
    if (v >= n) return;
    int boff = (blockIdx.x == 0) ? 0 : bsum[blockIdx.x - 1];
    int rs = boff + incl[v] - deg[v];   // exclusive scan
    row_start[v] = rs;
    cursor[v] = rs;
}

// dst-partitioned scatter (round 5): partition = blockIdx&7 keeps each 1.6 MB
// col window in one XCD's L2 -> full-line writebacks.
#define SCAT_EPB 8192
__global__ __launch_bounds__(256) void scatter_csr_part(
    const int* __restrict__ ei, int E, float inv_psz,
    int* __restrict__ cursor, int* __restrict__ col) {
    const int part = blockIdx.x & 7;
    const int base = (blockIdx.x >> 3) * SCAT_EPB;
    const int end = min(E, base + SCAT_EPB);
    for (int i = base + threadIdx.x; i < end; i += 256) {
        int d = ei[(size_t)E + i];
        int s = ei[i];
        int p = (int)((float)d * inv_psz);
        p = p > 7 ? 7 : p;
        if (p == part) {
            int pos = atomicAdd(&cursor[d], 1);
            col[pos] = s;
        }
    }
}

__device__ inline unsigned int pack2h(float a, float b) {
    __half ha = __float2half_rn(a), hb = __float2half_rn(b);
    unsigned short ua = *(unsigned short*)&ha, ub = *(unsigned short*)&hb;
    return (unsigned int)ua | ((unsigned int)ub << 16);
}

// Register-tiled GEMM: Hs = fp16( (X @ W) * dinv[row] ). 4x4 acc per thread,
// X tile in LDS, W float4 from global (L1-resident).
template <int FIN, int FOUT, int TM>
__global__ __launch_bounds__(256) void gemm_tile_h(
    const float* __restrict__ X, const float* __restrict__ W,
    const float* __restrict__ dinv, __half* __restrict__ Hs, int n) {
    constexpr int CT = FOUT / 4;          // col-groups
    constexpr int RG = 256 / CT;          // row-groups
    static_assert(TM == RG * 4, "tile mismatch");
    constexpr int LROW = FIN + 4;
    __shared__ float xs[TM][LROW];

    const int node0 = blockIdx.x * TM;
    const int tid = threadIdx.x;

    constexpr int C4 = FIN / 4;
    for (int i = tid; i < TM * C4; i += 256) {
        int r = i / C4, c = i % C4;
        float4 v = make_float4(0.f, 0.f, 0.f, 0.f);
        if (node0 + r < n) v = *(const float4*)(X + (size_t)(node0 + r) * FIN + c * 4);
        *(float4*)&xs[r][c * 4] = v;
    }
    __syncthreads();

    const int col = (tid % CT) * 4;
    const int r0 = (tid / CT) * 4;

    float acc[4][4];
#pragma unroll
    for (int i = 0; i < 4; ++i)
#pragma unroll
        for (int j = 0; j < 4; ++j) acc[i][j] = 0.f;

#pragma unroll 8
    for (int k = 0; k < FIN; ++k) {
        float4 b = *(const float4*)(W + (size_t)k * FOUT + col);
        float a0 = xs[r0 + 0][k];
        float a1 = xs[r0 + 1][k];
        float a2 = xs[r0 + 2][k];
        float a3 = xs[r0 + 3][k];
        acc[0][0] = fmaf(a0, b.x, acc[0][0]); acc[0][1] = fmaf(a0, b.y, acc[0][1]);
        acc[0][2] = fmaf(a0, b.z, acc[0][2]); acc[0][3] = fmaf(a0, b.w, acc[0][3]);
        acc[1][0] = fmaf(a1, b.x, acc[1][0]); acc[1][1] = fmaf(a1, b.y, acc[1][1]);
        acc[1][2] = fmaf(a1, b.z, acc[1][2]); acc[1][3] = fmaf(a1, b.w, acc[1][3]);
        acc[2][0] = fmaf(a2, b.x, acc[2][0]); acc[2][1] = fmaf(a2, b.y, acc[2][1]);
        acc[2][2] = fmaf(a2, b.z, acc[2][2]); acc[2][3] = fmaf(a2, b.w, acc[2][3]);
        acc[3][0] = fmaf(a3, b.x, acc[3][0]); acc[3][1] = fmaf(a3, b.y, acc[3][1]);
        acc[3][2] = fmaf(a3, b.z, acc[3][2]); acc[3][3] = fmaf(a3, b.w, acc[3][3]);
    }

#pragma unroll
    for (int rr = 0; rr < 4; ++rr) {
        int node = node0 + r0 + rr;
        if (node < n) {
            float di = dinv[node];
            uint2 pk;
            pk.x = pack2h(acc[rr][0] * di, acc[rr][1] * di);
            pk.y = pack2h(acc[rr][2] * di, acc[rr][3] * di);
            *(uint2*)(Hs + (size_t)node * FOUT + col) = pk;   // 8-B aligned
        }
    }
}

__device__ inline void add8h(float* acc, uint4 p) {
    unsigned int w[4] = {p.x, p.y, p.z, p.w};
#pragma unroll
    for (int t = 0; t < 4; ++t) {
        __half2 h = *(const __half2*)&w[t];
        float2 f = __half22float2(h);
        acc[2 * t] += f.x;
        acc[2 * t + 1] += f.y;
    }
}

// Pull aggregation + norm + bias + tanh from fp16 Hs. F/8 lanes per dst node,
// each lane owns 8 features (one uint4 = 16 B per gathered row); 4 neighbor
// rows in flight.
template <int F>
__global__ __launch_bounds__(256) void pull_agg_h(
    const int* __restrict__ row_start, const int* __restrict__ deg,
    const int* __restrict__ col, const __half* __restrict__ Hs,
    const float* __restrict__ dinv, const float* __restrict__ B,
    float* __restrict__ OUT, int n) {
    constexpr int TPE = F / 8;
    long long gid = (long long)blockIdx.x * 256 + threadIdx.x;
    int node = (int)(gid / TPE);
    int lane = (int)(gid % TPE);
    if (node >= n) return;
    const int beg = row_start[node];
    const int cnt = deg[node];
    const size_t lo = (size_t)lane * 8;

    float acc[8] = {0.f, 0.f, 0.f, 0.f, 0.f, 0.f, 0.f, 0.f};
    add8h(acc, *(const uint4*)(Hs + (size_t)node * F + lo));  // self term

    int j = 0;
    for (; j + 4 <= cnt; j += 4) {
        int s0 = col[beg + j + 0], s1 = col[beg + j + 1];
        int s2 = col[beg + j + 2], s3 = col[beg + j + 3];
        uint4 p0 = *(const uint4*)(Hs + (size_t)s0 * F + lo);
        uint4 p1 = *(const uint4*)(Hs + (size_t)s1 * F + lo);
        uint4 p2 = *(const uint4*)(Hs + (size_t)s2 * F + lo);
        uint4 p3 = *(const uint4*)(Hs + (size_t)s3 * F + lo);
        add8h(acc, p0); add8h(acc, p1); add8h(acc, p2); add8h(acc, p3);
    }
    for (; j < cnt; ++j) {
        int s = col[beg + j];
        add8h(acc, *(const uint4*)(Hs + (size_t)s * F + lo));
    }

    float di = dinv[node];
    float4 b0 = *(const float4*)(B + lo);
    float4 b1 = *(const float4*)(B + lo + 4);
    float4 r0, r1;
    r0.x = tanhf(fmaf(acc[0], di, b0.x));
    r0.y = tanhf(fmaf(acc[1], di, b0.y));
    r0.z = tanhf(fmaf(acc[2], di, b0.z));
    r0.w = tanhf(fmaf(acc[3], di, b0.w));
    r1.x = tanhf(fmaf(acc[4], di, b1.x));
    r1.y = tanhf(fmaf(acc[5], di, b1.y));
    r1.z = tanhf(fmaf(acc[6], di, b1.z));
    r1.w = tanhf(fmaf(acc[7], di, b1.w));
    float* op = OUT + (size_t)node * F + lo;
    *(float4*)(op) = r0;
    *(float4*)(op + 4) = r1;
}

__global__ void classifier_kernel(const float* __restrict__ Hf,
                                  const float* __restrict__ Wc,
                                  const float* __restrict__ bc,
                                  float* __restrict__ out, int n) {
    int v = blockIdx.x * blockDim.x + threadIdx.x;
    if (v >= n) return;
    float o0 = bc[0], o1 = bc[1];
    const float* h = Hf + (size_t)v * 16;
#pragma unroll
    for (int k = 0; k < 16; ++k) {
        float hv = h[k];
        o0 = fmaf(hv, Wc[k * 2 + 0], o0);
        o1 = fmaf(hv, Wc[k * 2 + 1], o1);
    }
    out[(size_t)v * 2 + 0] = o0;
    out[(size_t)v * 2 + 1] = o1;
}

extern "C" void kernel_launch(void* const* d_in, const int* in_sizes, int n_in,
                              void* d_out, int out_size, void* d_ws, size_t ws_size,
                              hipStream_t stream) {
    const float* x  = (const float*)d_in[0];
    const int* ei   = (const int*)d_in[1];   // int32 (harness converts)
    const float* W1 = (const float*)d_in[2];
    const float* b1 = (const float*)d_in[3];
    const float* W2 = (const float*)d_in[4];
    const float* b2 = (const float*)d_in[5];
    const float* W3 = (const float*)d_in[6];
    const float* b3 = (const float*)d_in[7];
    const float* Wc = (const float*)d_in[8];
    const float* bc = (const float*)d_in[9];

    const int n = in_sizes[0] / 256;
    const int E = in_sizes[1] / 2;
    const int nb = (n + 255) / 256;          // scan blocks (391 <= 512)

    float* outp = (float*)d_out;             // [n,2]
    float* outh = outp + (size_t)n * 2;      // [n,16]

    // workspace: deg | dinv | row_start | cursor | incl | bsum(512) | col(E)
    //            | HsH (half, n*128) | xbuf (float, n*128)
    int*    deg       = (int*)d_ws;
    float*  dinv      = (float*)d_ws + (size_t)n;
    int*    row_start = (int*)d_ws + 2 * (size_t)n;
    int*    cursor    = (int*)d_ws + 3 * (size_t)n;
    int*    incl      = (int*)d_ws + 4 * (size_t)n;
    int*    bsum      = (int*)d_ws + 5 * (size_t)n;
    int*    col       = bsum + 512;
    __half* HsH       = (__half*)(col + E);
    float*  xbuf      = (float*)(HsH + (size_t)n * 128);

    // --- CSR build (shared by all 3 layers) ---
    hipMemsetAsync(deg, 0, sizeof(int) * (size_t)n, stream);
    deg_count_kernel<<<(E + 255) / 256, 256, 0, stream>>>(ei, E, deg);
    dinv_kernel<<<nb, 256, 0, stream>>>(deg, dinv, n);
    scan_block<<<nb, 256, 0, stream>>>(deg, n, incl, bsum);
    scan_sums<<<1, 512, 0, stream>>>(bsum, nb);
    finalize_csr<<<nb, 256, 0, stream>>>(incl, bsum, deg, n, row_start, cursor);
    {
        int psz = (n + 7) / 8;
        float inv_psz = 1.0f / (float)psz;
        int chunks = (E + SCAT_EPB - 1) / SCAT_EPB;
        scatter_csr_part<<<chunks * 8, 256, 0, stream>>>(ei, E, inv_psz, cursor, col);
    }

    // --- layer 1: 256 -> 128 ---
    gemm_tile_h<256, 128, 32><<<(n + 31) / 32, 256, 0, stream>>>(x, W1, dinv, HsH, n);
    pull_agg_h<128><<<(int)(((long long)n * 16 + 255) / 256), 256, 0, stream>>>(
        row_start, deg, col, HsH, dinv, b1, xbuf, n);

    // --- layer 2: 128 -> 64 ---
    gemm_tile_h<128, 64, 64><<<(n + 63) / 64, 256, 0, stream>>>(xbuf, W2, dinv, HsH, n);
    pull_agg_h<64><<<(int)(((long long)n * 8 + 255) / 256), 256, 0, stream>>>(
        row_start, deg, col, HsH, dinv, b2, xbuf, n);   // x2 dead after gemm2

    // --- layer 3: 64 -> 16 ---
    gemm_tile_h<64, 16, 256><<<(n + 255) / 256, 256, 0, stream>>>(xbuf, W3, dinv, HsH, n);
    pull_agg_h<16><<<(int)(((long long)n * 2 + 255) / 256), 256, 0, stream>>>(
        row_start, deg, col, HsH, dinv, b3, outh, n);

    // --- classifier head ---
    classifier_kernel<<<(n + 255) / 256, 256, 0, stream>>>(outh, Wc, bc, outp, n);
}

// Round 7
// 725.949 us; speedup vs baseline: 13.2773x; 1.1243x over previous
//
#include <hip/hip_runtime.h>
#include <hip/hip_fp16.h>
#include <cstdint>
#include <cstddef>

// ---------------------------------------------------------------------------
// GCNClassifier: 3x (GCNConv + tanh) + linear head, N=100k nodes, E=3.2M edges
// Round 7: atomic-free CSR build. Round-6 counters showed scatter_csr_part
// writing 176 MB = ~55 B/edge: device-scope cursor atomics RMW at the
// coherence point (64-B EA transaction each) -- partitioning col stores never
// addressed the real cost. deg_count paid the same tax. Replacement:
// bucketed counting sort (LDS histograms + LDS cursors only):
//   hist[chunk][bucket] -> scan -> scatter into per-(bucket,chunk) regions
//   -> per-bucket exact CSR in LDS -> coalesced col/deg/row_start/dinv.
//   Hs[v]  = fp16( (X@W)[v] * dinv[v] )               (gemm epilogue)
//   out[v] = tanh( dinv[v]*(Hs[v] + sum_{u->v} Hs[u]) + b )   (pull, fused)
// edge_index arrives as int32.
// ---------------------------------------------------------------------------

#define EPB 16384        // edges per hist/scatter chunk
#define BSHIFT 8         // bucket = dst >> 8 (256 dst nodes per bucket)
#define NBUC_MAX 512     // 100000>>8 = 390 max bucket id
#define BCAP 12800       // bucket_build LDS edge capacity (avg 8192, 50+ sigma)

// --- generic two-level exclusive scan (reused from earlier rounds) ---
__global__ __launch_bounds__(256) void scan_block(const int* __restrict__ src, int n,
                                                  int* __restrict__ incl,
                                                  int* __restrict__ bsum) {
    int tid = threadIdx.x;
    int v = blockIdx.x * 256 + tid;
    int val = (v < n) ? src[v] : 0;
    int lane = tid & 63, w = tid >> 6;
#pragma unroll
    for (int off = 1; off < 64; off <<= 1) {
        int t = __shfl_up(val, off, 64);
        if (lane >= off) val += t;
    }
    __shared__ int wsum[4];
    if (lane == 63) wsum[w] = val;
    __syncthreads();
#pragma unroll
    for (int i = 0; i < 4; ++i)
        if (i < w) val += wsum[i];
    if (v < n) incl[v] = val;
    if (tid == 255) bsum[blockIdx.x] = val;
}

__global__ __launch_bounds__(512) void scan_sums(int* __restrict__ bsum, int nb) {
    int tid = threadIdx.x;              // nb <= 512
    int val = (tid < nb) ? bsum[tid] : 0;
    int lane = tid & 63, w = tid >> 6;
#pragma unroll
    for (int off = 1; off < 64; off <<= 1) {
        int t = __shfl_up(val, off, 64);
        if (lane >= off) val += t;
    }
    __shared__ int wsum[8];
    if (lane == 63) wsum[w] = val;
    __syncthreads();
#pragma unroll
    for (int i = 0; i < 8; ++i)
        if (i < w) val += wsum[i];
    if (tid < nb) bsum[tid] = val;
}

__global__ __launch_bounds__(256) void finalize_scan(
    const int* __restrict__ incl, const int* __restrict__ bsum,
    const int* __restrict__ src, int n, int* __restrict__ excl) {
    int v = blockIdx.x * 256 + threadIdx.x;
    if (v >= n) return;
    int boff = (blockIdx.x == 0) ? 0 : bsum[blockIdx.x - 1];
    excl[v] = boff + incl[v] - src[v];
}

// Pass A: per-chunk histogram over dst buckets (LDS atomics only).
__global__ __launch_bounds__(256) void hist_bucket(
    const int* __restrict__ ei, int E, int nbuc, int nch,
    int* __restrict__ histG) {
    __shared__ int h[NBUC_MAX];
    const int k = blockIdx.x;
    for (int b = threadIdx.x; b < NBUC_MAX; b += 256) h[b] = 0;
    __syncthreads();
    const int base = k * EPB, end = min(E, base + EPB);
    for (int i = base + threadIdx.x; i < end; i += 256)
        atomicAdd(&h[ei[(size_t)E + i] >> BSHIFT], 1);
    __syncthreads();
    for (int b = threadIdx.x; b < nbuc; b += 256)
        histG[(size_t)b * nch + k] = h[b];
}

// Pass C: scatter (src,dst) pairs into per-(bucket,chunk) contiguous regions.
// LDS cursors; each region's stores are sequential -> full-line writebacks.
__global__ __launch_bounds__(256) void bucket_scatter(
    const int* __restrict__ ei, int E, int nbuc, int nch,
    const int* __restrict__ offs, uint2* __restrict__ ebuf) {
    __shared__ int cur[NBUC_MAX];
    const int k = blockIdx.x;
    for (int b = threadIdx.x; b < nbuc; b += 256)
        cur[b] = offs[(size_t)b * nch + k];
    __syncthreads();
    const int base = k * EPB, end = min(E, base + EPB);
    for (int i = base + threadIdx.x; i < end; i += 256) {
        int s = ei[i];
        int d = ei[(size_t)E + i];
        int pos = atomicAdd(&cur[d >> BSHIFT], 1);
        ebuf[pos] = make_uint2((unsigned)s, (unsigned)d);
    }
}

// Pass D: one block per bucket -> exact CSR slice + deg/row_start/dinv.
__global__ __launch_bounds__(256) void bucket_build(
    const uint2* __restrict__ ebuf, const int* __restrict__ offs,
    int E, int nbuc, int nch, int n,
    int* __restrict__ col, int* __restrict__ deg,
    int* __restrict__ row_start, float* __restrict__ dinv) {
    const int b = blockIdx.x;
    const int tid = threadIdx.x;
    const int estart = offs[(size_t)b * nch];
    const int eend = (b + 1 < nbuc) ? offs[(size_t)(b + 1) * nch] : E;
    const int cnt = eend - estart;

    __shared__ int degl[256];
    __shared__ int curl[256];
    __shared__ int wsum[4];
    __shared__ int colstage[BCAP];

    degl[tid] = 0;
    __syncthreads();
    // phase 1: per-dst counts
    for (int i = tid; i < cnt; i += 256)
        atomicAdd(&degl[ebuf[estart + i].y & 255], 1);
    __syncthreads();
    // phase 2: 256-wide exclusive scan of degl
    int myDeg = degl[tid];
    int val = myDeg;
    int lane = tid & 63, w = tid >> 6;
#pragma unroll
    for (int off = 1; off < 64; off <<= 1) {
        int t = __shfl_up(val, off, 64);
        if (lane >= off) val += t;
    }
    if (lane == 63) wsum[w] = val;
    __syncthreads();
#pragma unroll
    for (int i = 0; i < 4; ++i)
        if (i < w) val += wsum[i];
    int excl = val - myDeg;
    curl[tid] = excl;
    int v = (b << BSHIFT) + tid;
    if (v < n) {
        deg[v] = myDeg;
        row_start[v] = estart + excl;
        dinv[v] = rsqrtf((float)(myDeg + 1));   // +1 self loop
    }
    __syncthreads();
    // phase 3+4: place srcs (LDS-staged, coalesced writeback)
    if (cnt <= BCAP) {
        for (int i = tid; i < cnt; i += 256) {
            uint2 e = ebuf[estart + i];
            int pos = atomicAdd(&curl[e.y & 255], 1);
            colstage[pos] = (int)e.x;
        }
        __syncthreads();
        for (int i = tid; i < cnt; i += 256)
            col[estart + i] = colstage[i];
    } else {  // safety fallback (never expected for random uniform dsts)
        for (int i = tid; i < cnt; i += 256) {
            uint2 e = ebuf[estart + i];
            int pos = atomicAdd(&curl[e.y & 255], 1);
            col[estart + pos] = (int)e.x;
        }
    }
}

__device__ inline unsigned int pack2h(float a, float b) {
    __half ha = __float2half_rn(a), hb = __float2half_rn(b);
    unsigned short ua = *(unsigned short*)&ha, ub = *(unsigned short*)&hb;
    return (unsigned int)ua | ((unsigned int)ub << 16);
}

// Register-tiled GEMM: Hs = fp16( (X @ W) * dinv[row] ). 4x4 acc per thread,
// X tile in LDS, W float4 from global (L1-resident).
template <int FIN, int FOUT, int TM>
__global__ __launch_bounds__(256) void gemm_tile_h(
    const float* __restrict__ X, const float* __restrict__ W,
    const float* __restrict__ dinv, __half* __restrict__ Hs, int n) {
    constexpr int CT = FOUT / 4;
    constexpr int RG = 256 / CT;
    static_assert(TM == RG * 4, "tile mismatch");
    constexpr int LROW = FIN + 4;
    __shared__ float xs[TM][LROW];

    const int node0 = blockIdx.x * TM;
    const int tid = threadIdx.x;

    constexpr int C4 = FIN / 4;
    for (int i = tid; i < TM * C4; i += 256) {
        int r = i / C4, c = i % C4;
        float4 v = make_float4(0.f, 0.f, 0.f, 0.f);
        if (node0 + r < n) v = *(const float4*)(X + (size_t)(node0 + r) * FIN + c * 4);
        *(float4*)&xs[r][c * 4] = v;
    }
    __syncthreads();

    const int col = (tid % CT) * 4;
    const int r0 = (tid / CT) * 4;

    float acc[4][4];
#pragma unroll
    for (int i = 0; i < 4; ++i)
#pragma unroll
        for (int j = 0; j < 4; ++j) acc[i][j] = 0.f;

#pragma unroll 8
    for (int k = 0; k < FIN; ++k) {
        float4 b = *(const float4*)(W + (size_t)k * FOUT + col);
        float a0 = xs[r0 + 0][k];
        float a1 = xs[r0 + 1][k];
        float a2 = xs[r0 + 2][k];
        float a3 = xs[r0 + 3][k];
        acc[0][0] = fmaf(a0, b.x, acc[0][0]); acc[0][1] = fmaf(a0, b.y, acc[0][1]);
        acc[0][2] = fmaf(a0, b.z, acc[0][2]); acc[0][3] = fmaf(a0, b.w, acc[0][3]);
        acc[1][0] = fmaf(a1, b.x, acc[1][0]); acc[1][1] = fmaf(a1, b.y, acc[1][1]);
        acc[1][2] = fmaf(a1, b.z, acc[1][2]); acc[1][3] = fmaf(a1, b.w, acc[1][3]);
        acc[2][0] = fmaf(a2, b.x, acc[2][0]); acc[2][1] = fmaf(a2, b.y, acc[2][1]);
        acc[2][2] = fmaf(a2, b.z, acc[2][2]); acc[2][3] = fmaf(a2, b.w, acc[2][3]);
        acc[3][0] = fmaf(a3, b.x, acc[3][0]); acc[3][1] = fmaf(a3, b.y, acc[3][1]);
        acc[3][2] = fmaf(a3, b.z, acc[3][2]); acc[3][3] = fmaf(a3, b.w, acc[3][3]);
    }

#pragma unroll
    for (int rr = 0; rr < 4; ++rr) {
        int node = node0 + r0 + rr;
        if (node < n) {
            float di = dinv[node];
            uint2 pk;
            pk.x = pack2h(acc[rr][0] * di, acc[rr][1] * di);
            pk.y = pack2h(acc[rr][2] * di, acc[rr][3] * di);
            *(uint2*)(Hs + (size_t)node * FOUT + col) = pk;
        }
    }
}

__device__ inline void add8h(float* acc, uint4 p) {
    unsigned int w[4] = {p.x, p.y, p.z, p.w};
#pragma unroll
    for (int t = 0; t < 4; ++t) {
        __half2 h = *(const __half2*)&w[t];
        float2 f = __half22float2(h);
        acc[2 * t] += f.x;
        acc[2 * t + 1] += f.y;
    }
}

// Pull aggregation + norm + bias + tanh from fp16 Hs. F/8 lanes per dst node.
template <int F>
__global__ __launch_bounds__(256) void pull_agg_h(
    const int* __restrict__ row_start, const int* __restrict__ deg,
    const int* __restrict__ col, const __half* __restrict__ Hs,
    const float* __restrict__ dinv, const float* __restrict__ B,
    float* __restrict__ OUT, int n) {
    constexpr int TPE = F / 8;
    long long gid = (long long)blockIdx.x * 256 + threadIdx.x;
    int node = (int)(gid / TPE);
    int lane = (int)(gid % TPE);
    if (node >= n) return;
    const int beg = row_start[node];
    const int cnt = deg[node];
    const size_t lo = (size_t)lane * 8;

    float acc[8] = {0.f, 0.f, 0.f, 0.f, 0.f, 0.f, 0.f, 0.f};
    add8h(acc, *(const uint4*)(Hs + (size_t)node * F + lo));  // self term

    int j = 0;
    for (; j + 4 <= cnt; j += 4) {
        int s0 = col[beg + j + 0], s1 = col[beg + j + 1];
        int s2 = col[beg + j + 2], s3 = col[beg + j + 3];
        uint4 p0 = *(const uint4*)(Hs + (size_t)s0 * F + lo);
        uint4 p1 = *(const uint4*)(Hs + (size_t)s1 * F + lo);
        uint4 p2 = *(const uint4*)(Hs + (size_t)s2 * F + lo);
        uint4 p3 = *(const uint4*)(Hs + (size_t)s3 * F + lo);
        add8h(acc, p0); add8h(acc, p1); add8h(acc, p2); add8h(acc, p3);
    }
    for (; j < cnt; ++j) {
        int s = col[beg + j];
        add8h(acc, *(const uint4*)(Hs + (size_t)s * F + lo));
    }

    float di = dinv[node];
    float4 b0 = *(const float4*)(B + lo);
    float4 b1 = *(const float4*)(B + lo + 4);
    float4 r0, r1;
    r0.x = tanhf(fmaf(acc[0], di, b0.x));
    r0.y = tanhf(fmaf(acc[1], di, b0.y));
    r0.z = tanhf(fmaf(acc[2], di, b0.z));
    r0.w = tanhf(fmaf(acc[3], di, b0.w));
    r1.x = tanhf(fmaf(acc[4], di, b1.x));
    r1.y = tanhf(fmaf(acc[5], di, b1.y));
    r1.z = tanhf(fmaf(acc[6], di, b1.z));
    r1.w = tanhf(fmaf(acc[7], di, b1.w));
    float* op = OUT + (size_t)node * F + lo;
    *(float4*)(op) = r0;
    *(float4*)(op + 4) = r1;
}

__global__ void classifier_kernel(const float* __restrict__ Hf,
                                  const float* __restrict__ Wc,
                                  const float* __restrict__ bc,
                                  float* __restrict__ out, int n) {
    int v = blockIdx.x * blockDim.x + threadIdx.x;
    if (v >= n) return;
    float o0 = bc[0], o1 = bc[1];
    const float* h = Hf + (size_t)v * 16;
#pragma unroll
    for (int k = 0; k < 16; ++k) {
        float hv = h[k];
        o0 = fmaf(hv, Wc[k * 2 + 0], o0);
        o1 = fmaf(hv, Wc[k * 2 + 1], o1);
    }
    out[(size_t)v * 2 + 0] = o0;
    out[(size_t)v * 2 + 1] = o1;
}

extern "C" void kernel_launch(void* const* d_in, const int* in_sizes, int n_in,
                              void* d_out, int out_size, void* d_ws, size_t ws_size,
                              hipStream_t stream) {
    const float* x  = (const float*)d_in[0];
    const int* ei   = (const int*)d_in[1];   // int32 (harness converts)
    const float* W1 = (const float*)d_in[2];
    const float* b1 = (const float*)d_in[3];
    const float* W2 = (const float*)d_in[4];
    const float* b2 = (const float*)d_in[5];
    const float* W3 = (const float*)d_in[6];
    const float* b3 = (const float*)d_in[7];
    const float* Wc = (const float*)d_in[8];
    const float* bc = (const float*)d_in[9];

    const int n = in_sizes[0] / 256;
    const int E = in_sizes[1] / 2;
    const int nbuc = (n + 255) >> BSHIFT;          // 391
    const int nch  = (E + EPB - 1) / EPB;          // 196
    const int NH   = nbuc * nch;                   // 76,636
    const int nb2  = (NH + 255) / 256;             // 300 <= 512

    float* outp = (float*)d_out;             // [n,2]
    float* outh = outp + (size_t)n * 2;      // [n,16]

    // workspace: deg|dinv|row_start | histG|incl|bsum(512)|offs | col(E)
    //            | HsH (half n*128) | xbuf (float n*128, aliases ebuf)
    int*    deg       = (int*)d_ws;
    float*  dinv      = (float*)d_ws + (size_t)n;
    int*    row_start = (int*)d_ws + 2 * (size_t)n;
    int*    histG     = (int*)d_ws + 3 * (size_t)n;
    int*    incl      = histG + NH;
    int*    bsum      = incl + NH;
    int*    offs      = bsum + 512;
    int*    col       = offs + NH;
    __half* HsH       = (__half*)(col + E);
    float*  xbuf      = (float*)(HsH + (size_t)n * 128);
    uint2*  ebuf      = (uint2*)xbuf;        // alias: dead before pull1 writes xbuf

    // --- atomic-free CSR build (shared by all 3 layers) ---
    hist_bucket<<<nch, 256, 0, stream>>>(ei, E, nbuc, nch, histG);
    scan_block<<<nb2, 256, 0, stream>>>(histG, NH, incl, bsum);
    scan_sums<<<1, 512, 0, stream>>>(bsum, nb2);
    finalize_scan<<<nb2, 256, 0, stream>>>(incl, bsum, histG, NH, offs);
    bucket_scatter<<<nch, 256, 0, stream>>>(ei, E, nbuc, nch, offs, ebuf);
    bucket_build<<<nbuc, 256, 0, stream>>>(ebuf, offs, E, nbuc, nch, n,
                                           col, deg, row_start, dinv);

    // --- layer 1: 256 -> 128 ---
    gemm_tile_h<256, 128, 32><<<(n + 31) / 32, 256, 0, stream>>>(x, W1, dinv, HsH, n);
    pull_agg_h<128><<<(int)(((long long)n * 16 + 255) / 256), 256, 0, stream>>>(
        row_start, deg, col, HsH, dinv, b1, xbuf, n);

    // --- layer 2: 128 -> 64 ---
    gemm_tile_h<128, 64, 64><<<(n + 63) / 64, 256, 0, stream>>>(xbuf, W2, dinv, HsH, n);
    pull_agg_h<64><<<(int)(((long long)n * 8 + 255) / 256), 256, 0, stream>>>(
        row_start, deg, col, HsH, dinv, b2, xbuf, n);

    // --- layer 3: 64 -> 16 ---
    gemm_tile_h<64, 16, 256><<<(n + 255) / 256, 256, 0, stream>>>(xbuf, W3, dinv, HsH, n);
    pull_agg_h<16><<<(int)(((long long)n * 2 + 255) / 256), 256, 0, stream>>>(
        row_start, deg, col, HsH, dinv, b3, outh, n);

    // --- classifier head ---
    classifier_kernel<<<(n + 255) / 256, 256, 0, stream>>>(outh, Wc, bc, outp, n);
}